// Round 1
// baseline (1089.698 us; speedup 1.0000x reference)
//
#include <hip/hip_runtime.h>

#define HW    16384   // 128*128
#define CIN   64
#define MCH   48
// encoder: 100 outputs = 4 groups x 25

// --- prep: transpose w_encoder [100][48][3][3] -> we_t[(m*9+t)*128 + g*32 + k]
__global__ void prep_weights(const float* __restrict__ we, float* __restrict__ we_t) {
    int idx = blockIdx.x * 256 + threadIdx.x;      // over 432*100
    if (idx >= 432 * 100) return;
    int mt = idx / 100;        // m*9 + t
    int e  = idx % 100;
    int g = e / 25, k = e % 25;
    we_t[mt * 128 + g * 32 + k] = we[e * 432 + mt];
}

// --- kernel A: fused compress(1x1)+relu -> encoder(3x3) -> softmax(25) per 8x8 tile
__global__ __launch_bounds__(256, 2)
void carafe_weights(const float* __restrict__ x,
                    const float* __restrict__ wc,   // [48][64]
                    const float* __restrict__ bc,   // [48]
                    const float* __restrict__ we_t, // [432][128] padded
                    const float* __restrict__ be,   // [100]
                    float* __restrict__ wnorm) {    // [8][100][128][128]
    __shared__ float lds_x[CIN * 100];    // [c][pos] pos=10x10 halo
    __shared__ float lds_y1[MCH * 100];   // [m][pos]
    __shared__ float lds_wc[CIN * MCH];   // [c][m]

    const int tid  = threadIdx.x;
    const int blk  = blockIdx.x;          // 8 * 256 tiles
    const int b    = blk >> 8;
    const int tile = blk & 255;
    const int h0 = (tile >> 4) * 8, w0 = (tile & 15) * 8;

    // stage transposed compress weights
    for (int i = tid; i < CIN * MCH; i += 256) {
        int c = i / MCH, m = i % MCH;
        lds_wc[i] = wc[m * CIN + c];
    }
    // stage x halo tile (10x10, zero outside image)
    const float* xb = x + b * CIN * HW;
    for (int i = tid; i < CIN * 100; i += 256) {
        int c = i / 100, pos = i % 100;
        int hy = h0 - 1 + pos / 10;
        int wx = w0 - 1 + pos % 10;
        float v = 0.f;
        if (hy >= 0 && hy < 128 && wx >= 0 && wx < 128)
            v = xb[c * HW + hy * 128 + wx];
        lds_x[c * 100 + pos] = v;
    }
    __syncthreads();

    // y1 = relu(conv1x1 + bias); zero outside image (conv3x3 pad semantics)
    for (int i = tid; i < MCH * 100; i += 256) {
        int m = i / 100, pos = i % 100;
        int hy = h0 - 1 + pos / 10;
        int wx = w0 - 1 + pos % 10;
        float acc = bc[m];
        #pragma unroll
        for (int c = 0; c < CIN; ++c)
            acc = fmaf(lds_x[c * 100 + pos], lds_wc[c * MCH + m], acc);
        bool inimg = (hy >= 0) && (hy < 128) && (wx >= 0) && (wx < 128);
        lds_y1[m * 100 + pos] = inimg ? fmaxf(acc, 0.f) : 0.f;
    }
    __syncthreads();

    // conv3x3: wave g = tid>>6 owns softmax group g; thread = 1 pixel, acc[25]
    const int g   = tid >> 6;
    const int pix = tid & 63;
    const int py = pix >> 3, px = pix & 7;

    float acc[25];
    #pragma unroll
    for (int e = 0; e < 25; ++e) acc[e] = be[g * 25 + e];

    #pragma unroll 1
    for (int m = 0; m < MCH; ++m) {
        #pragma unroll
        for (int t = 0; t < 9; ++t) {
            float v = lds_y1[m * 100 + (py + t / 3) * 10 + (px + t % 3)];
            const float* wr = we_t + (m * 9 + t) * 128 + g * 32;  // 128B aligned
            #pragma unroll
            for (int i4 = 0; i4 < 6; ++i4) {
                float4 wv = *(const float4*)(wr + 4 * i4);
                acc[4 * i4 + 0] = fmaf(v, wv.x, acc[4 * i4 + 0]);
                acc[4 * i4 + 1] = fmaf(v, wv.y, acc[4 * i4 + 1]);
                acc[4 * i4 + 2] = fmaf(v, wv.z, acc[4 * i4 + 2]);
                acc[4 * i4 + 3] = fmaf(v, wv.w, acc[4 * i4 + 3]);
            }
            acc[24] = fmaf(v, wr[24], acc[24]);
        }
    }

    // softmax over 25
    float mx = acc[0];
    #pragma unroll
    for (int e = 1; e < 25; ++e) mx = fmaxf(mx, acc[e]);
    float sum = 0.f;
    #pragma unroll
    for (int e = 0; e < 25; ++e) { acc[e] = __expf(acc[e] - mx); sum += acc[e]; }
    float inv = 1.f / sum;

    const int h = h0 + py, w = w0 + px;
    float* wp = wnorm + ((size_t)b * 100 + g * 25) * HW + h * 128 + w;
    #pragma unroll
    for (int e = 0; e < 25; ++e) wp[(size_t)e * HW] = acc[e] * inv;
}

// --- kernel B: weighted 5x5 patch gather + pixel shuffle
__global__ __launch_bounds__(256, 2)
void carafe_apply(const float* __restrict__ x,
                  const float* __restrict__ wnorm,
                  float* __restrict__ out) {
    const int p = blockIdx.x * 256 + threadIdx.x;   // 131072 pixels
    const int b   = p >> 14;
    const int rem = p & 16383;
    const int h = rem >> 7, w = rem & 127;

    // load 100 normalized weights into registers
    float wt[100];
    const float* wp = wnorm + (size_t)b * 100 * HW + rem;
    #pragma unroll
    for (int j = 0; j < 100; ++j) wt[j] = wp[(size_t)j * HW];

    // precompute clamped tap offsets; fold border mask into weights
    int off[25];
    #pragma unroll
    for (int ki = 0; ki < 5; ++ki) {
        #pragma unroll
        for (int kj = 0; kj < 5; ++kj) {
            int hy = h + ki - 2, wx = w + kj - 2;
            bool ok = (hy >= 0) && (hy < 128) && (wx >= 0) && (wx < 128);
            int k = ki * 5 + kj;
            off[k] = ok ? hy * 128 + wx : 0;
            float msk = ok ? 1.f : 0.f;
            wt[k]      *= msk;
            wt[25 + k] *= msk;
            wt[50 + k] *= msk;
            wt[75 + k] *= msk;
        }
    }

    const float* xb = x + (size_t)b * CIN * HW;
    float* ob = out + (size_t)b * CIN * 4 * HW;     // 64 ch x 256 x 256

    #pragma unroll 2
    for (int c = 0; c < CIN; c += 2) {
        float a00 = 0.f, a01 = 0.f, a10 = 0.f, a11 = 0.f;
        float a20 = 0.f, a21 = 0.f, a30 = 0.f, a31 = 0.f;
        const float* x0 = xb + c * HW;
        const float* x1 = x0 + HW;
        #pragma unroll
        for (int k = 0; k < 25; ++k) {
            float v0 = x0[off[k]];
            float v1 = x1[off[k]];
            a00 = fmaf(wt[k],      v0, a00);  a01 = fmaf(wt[k],      v1, a01);
            a10 = fmaf(wt[25 + k], v0, a10);  a11 = fmaf(wt[25 + k], v1, a11);
            a20 = fmaf(wt[50 + k], v0, a20);  a21 = fmaf(wt[50 + k], v1, a21);
            a30 = fmaf(wt[75 + k], v0, a30);  a31 = fmaf(wt[75 + k], v1, a31);
        }
        // ch = s*64+c  ->  q = s*16 + (c>>2), r1 = (c>>1)&1, r2 = c&1
        const int r1 = (c >> 1) & 1;
        const int oh = 2 * h + r1;
        const int ow = 2 * w;
        const int cq = c >> 2;
        float2 v0 = make_float2(a00, a01);
        float2 v1 = make_float2(a10, a11);
        float2 v2 = make_float2(a20, a21);
        float2 v3 = make_float2(a30, a31);
        *(float2*)(ob + (((size_t)(0 * 16 + cq) * 256 + oh) * 256 + ow)) = v0;
        *(float2*)(ob + (((size_t)(1 * 16 + cq) * 256 + oh) * 256 + ow)) = v1;
        *(float2*)(ob + (((size_t)(2 * 16 + cq) * 256 + oh) * 256 + ow)) = v2;
        *(float2*)(ob + (((size_t)(3 * 16 + cq) * 256 + oh) * 256 + ow)) = v3;
    }
}

extern "C" void kernel_launch(void* const* d_in, const int* in_sizes, int n_in,
                              void* d_out, int out_size, void* d_ws, size_t ws_size,
                              hipStream_t stream) {
    const float* x  = (const float*)d_in[0];   // [8][64][128][128]
    const float* wc = (const float*)d_in[1];   // [48][64][1][1]
    const float* bc = (const float*)d_in[2];   // [48]
    const float* we = (const float*)d_in[3];   // [100][48][3][3]
    const float* be = (const float*)d_in[4];   // [100]
    float* out = (float*)d_out;                // [8][64][256][256]

    // ws layout: we_t (432*128 floats = 216KB, rounded to 256KB) | wnorm (52.4MB)
    float* we_t  = (float*)d_ws;
    float* wnorm = (float*)((char*)d_ws + (256 * 1024));

    prep_weights<<<(432 * 100 + 255) / 256, 256, 0, stream>>>(we, we_t);
    carafe_weights<<<8 * 256, 256, 0, stream>>>(x, wc, bc, we_t, be, wnorm);
    carafe_apply<<<131072 / 256, 256, 0, stream>>>(x, wnorm, out);
}

// Round 6
// 415.209 us; speedup vs baseline: 2.6245x; 2.6245x over previous
//
#include <hip/hip_runtime.h>

#define HW 16384   // 128*128

typedef __bf16 bf16x8 __attribute__((ext_vector_type(8)));
typedef float  f32x4  __attribute__((ext_vector_type(4)));

// ---------- prep 1: x [b][64][128][128] f32 -> x_t [b][pos][64] bf16 ----------
__global__ __launch_bounds__(256)
void prep_xt(const float* __restrict__ x, __bf16* __restrict__ xt) {
    __shared__ float lds[256 * 65];
    const int b = blockIdx.x >> 6, chunk = blockIdx.x & 63;
    const int t = threadIdx.x;
    const int pos0 = chunk * 256;
    const float* xb = x + (size_t)b * 64 * HW + pos0;
    for (int c = 0; c < 64; ++c)
        lds[t * 65 + c] = xb[(size_t)c * HW + t];      // coalesced over t
    __syncthreads();
    __bf16* o = xt + ((size_t)b * HW + pos0 + t) * 64;
    #pragma unroll
    for (int j = 0; j < 8; ++j) {
        bf16x8 v;
        #pragma unroll
        for (int e = 0; e < 8; ++e) v[e] = (__bf16)lds[t * 65 + j * 8 + e];
        *(bf16x8*)(o + j * 8) = v;
    }
}

// ---------- prep 2: w_t[112][448] bf16 (k = t*48+m), wc_bf[48][64] bf16 ----------
__global__ __launch_bounds__(256)
void prep_w(const float* __restrict__ we, const float* __restrict__ wc,
            __bf16* __restrict__ wt, __bf16* __restrict__ wcb) {
    int idx = blockIdx.x * 256 + threadIdx.x;
    if (idx < 112 * 448) {
        int e = idx / 448, k = idx % 448;
        float v = 0.f;
        if (e < 100 && k < 432) {
            int t = k / 48, m = k % 48;
            v = we[(e * 48 + m) * 9 + t];
        }
        wt[idx] = (__bf16)v;
    } else {
        idx -= 112 * 448;
        if (idx < 48 * 64) wcb[idx] = (__bf16)wc[idx];
    }
}

// ---------- fused: conv1x1(MFMA) -> conv3x3(MFMA) -> softmax -> apply ----------
__global__ __launch_bounds__(256, 2)
void carafe_fused(const float* __restrict__ x, const __bf16* __restrict__ xt,
                  const __bf16* __restrict__ wcb, const float* __restrict__ bc,
                  const __bf16* __restrict__ wt, const float* __restrict__ be,
                  float* __restrict__ out) {
    __shared__ __align__(16) char smem[59392];
    __bf16*    y1  = (__bf16*)smem;    // [344][56] (rows=halo pos 18x18 pad + K-pad rows)
    _Float16*  lgt = (_Float16*)smem;  // [256][116] logits (union, after barrier)

    const int tid = threadIdx.x;
    const int lane = tid & 63, wv = tid >> 6;
    const int lgp = lane >> 4, lr = lane & 15;
    const int b = blockIdx.x >> 6, tile = blockIdx.x & 63;
    const int h0 = (tile >> 3) << 4, w0 = (tile & 7) << 4;

    // ===== P1: y1[pos][m] = relu(conv1x1)  via MFMA, M=336 pos, N=48, K=64
    bf16x8 bw[3][2];
    float bias1[3];
    #pragma unroll
    for (int nt = 0; nt < 3; ++nt) {
        bias1[nt] = bc[nt * 16 + lr];
        #pragma unroll
        for (int kc = 0; kc < 2; ++kc)
            bw[nt][kc] = *(const bf16x8*)(wcb + (nt * 16 + lr) * 64 + kc * 32 + lgp * 8);
    }
    for (int pt = wv; pt < 21; pt += 4) {
        int pos = pt * 16 + lr;
        int pr = (pos * 1821) >> 15;  int pc = pos - pr * 18;   // pos/18, pos%18
        int hy = h0 - 1 + pr, wx = w0 - 1 + pc;
        bool ok = (hy >= 0) & (hy < 128) & (wx >= 0) & (wx < 128);
        const __bf16* ap = xt + ((size_t)b * HW + (ok ? (hy * 128 + wx) : 0)) * 64 + lgp * 8;
        bf16x8 a0 = *(const bf16x8*)ap;
        bf16x8 a1 = *(const bf16x8*)(ap + 32);
        if (!ok) {
            #pragma unroll
            for (int e = 0; e < 8; ++e) { a0[e] = (__bf16)0.f; a1[e] = (__bf16)0.f; }
        }
        #pragma unroll
        for (int nt = 0; nt < 3; ++nt) {
            f32x4 cc = {bias1[nt], bias1[nt], bias1[nt], bias1[nt]};
            cc = __builtin_amdgcn_mfma_f32_16x16x32_bf16(a0, bw[nt][0], cc, 0, 0, 0);
            cc = __builtin_amdgcn_mfma_f32_16x16x32_bf16(a1, bw[nt][1], cc, 0, 0, 0);
            #pragma unroll
            for (int r = 0; r < 4; ++r) {
                int posw = pt * 16 + lgp * 4 + r;
                int pr2 = (posw * 1821) >> 15;  int pc2 = posw - pr2 * 18;
                int hy2 = h0 - 1 + pr2, wx2 = w0 - 1 + pc2;
                bool ok2 = (hy2 >= 0) & (hy2 < 128) & (wx2 >= 0) & (wx2 < 128);
                float v = ok2 ? fmaxf(cc[r], 0.f) : 0.f;   // zero padding for conv3x3
                y1[posw * 56 + nt * 16 + lr] = (__bf16)v;
            }
        }
    }
    // NaN fix: K-padding (t=9) in P2 reads y1 rows 336..339; zero them so that
    // garbage-bits-as-bf16 (possibly NaN/Inf) never enter MFMA (NaN*0 = NaN).
    for (int i = tid; i < 448; i += 256)
        y1[336 * 56 + i] = (__bf16)0.f;          // rows 336..343
    __syncthreads();

    // ===== P2: logits[256px][112out] = Ycol[px][432] * W[432][112], K=14x32
    f32x4 acc[4][7];
    #pragma unroll
    for (int ot = 0; ot < 7; ++ot) {
        int o_ = ot * 16 + lr;
        float bz = (o_ < 100) ? be[o_] : 0.f;
        #pragma unroll
        for (int i = 0; i < 4; ++i) acc[i][ot] = {bz, bz, bz, bz};
    }
    const int ptg0 = wv * 4;   // this wave's 4 pixel-row tiles

    auto ldA = [&](bf16x8 A[4], int kc) {
        int Kb = kc * 32 + lgp * 8;
        int t  = (Kb * 683) >> 15;  int m0 = Kb - t * 48;   // k = t*48+m
        int ty = (t * 11) >> 5;     int tx = t - ty * 3;
        int base = ty * 18 + lr + tx;
        #pragma unroll
        for (int i = 0; i < 4; ++i)
            A[i] = *(const bf16x8*)(y1 + ((ptg0 + i) * 18 + base) * 56 + m0);
    };
    auto ldB = [&](bf16x8 B[7], int kc) {
        #pragma unroll
        for (int j = 0; j < 7; ++j)
            B[j] = *(const bf16x8*)(wt + (j * 16 + lr) * 448 + kc * 32 + lgp * 8);
    };
    auto mm = [&](bf16x8 A[4], bf16x8 B[7]) {
        #pragma unroll
        for (int i = 0; i < 4; ++i)
            #pragma unroll
            for (int j = 0; j < 7; ++j)
                acc[i][j] = __builtin_amdgcn_mfma_f32_16x16x32_bf16(A[i], B[j], acc[i][j], 0, 0, 0);
    };

    bf16x8 A0[4], B0[7], A1[4], B1[7];
    ldA(A0, 0); ldB(B0, 0);
    #pragma unroll
    for (int kc = 0; kc < 14; kc += 2) {
        if (kc + 1 < 14) { ldA(A1, kc + 1); ldB(B1, kc + 1); }
        mm(A0, B0);
        if (kc + 2 < 14) { ldA(A0, kc + 2); ldB(B0, kc + 2); }
        if (kc + 1 < 14) mm(A1, B1);
    }
    __syncthreads();   // all waves done reading y1

    // ===== P3: spill logits to LDS [256][116] as fp16 (better mantissa than bf16)
    #pragma unroll
    for (int i = 0; i < 4; ++i)
        #pragma unroll
        for (int j = 0; j < 7; ++j) {
            int o_ = j * 16 + lr;
            #pragma unroll
            for (int r = 0; r < 4; ++r) {
                int p = (ptg0 + i) * 16 + lgp * 4 + r;
                lgt[p * 116 + o_] = (_Float16)acc[i][j][r];
            }
        }
    __syncthreads();

    // ===== P4: per-pixel softmax(25) x4 groups + 5x5 weighted gather + pixel shuffle
    const int p = tid;
    const int py = p >> 4, px = p & 15;
    const int h = h0 + py, w = w0 + px;

    float wt_[100];
    const _Float16* lrow = lgt + p * 116;
    #pragma unroll
    for (int g = 0; g < 4; ++g) {
        float v[25];
        #pragma unroll
        for (int k = 0; k < 25; ++k) v[k] = (float)lrow[g * 25 + k];
        float mx = v[0];
        #pragma unroll
        for (int k = 1; k < 25; ++k) mx = fmaxf(mx, v[k]);
        float s = 0.f;
        #pragma unroll
        for (int k = 0; k < 25; ++k) { v[k] = __expf(v[k] - mx); s += v[k]; }
        float inv = 1.f / s;
        #pragma unroll
        for (int k = 0; k < 25; ++k) wt_[g * 25 + k] = v[k] * inv;
    }

    int off[25];
    #pragma unroll
    for (int ki = 0; ki < 5; ++ki)
        #pragma unroll
        for (int kj = 0; kj < 5; ++kj) {
            int hy = h + ki - 2, wx = w + kj - 2;
            bool okk = (hy >= 0) && (hy < 128) && (wx >= 0) && (wx < 128);
            int k = ki * 5 + kj;
            off[k] = okk ? hy * 128 + wx : 0;
            float msk = okk ? 1.f : 0.f;
            wt_[k] *= msk; wt_[25 + k] *= msk; wt_[50 + k] *= msk; wt_[75 + k] *= msk;
        }

    const float* xb = x + (size_t)b * 64 * HW;
    float* ob = out + (size_t)b * 256 * HW;
    #pragma unroll 2
    for (int c = 0; c < 64; c += 2) {
        float a00 = 0.f, a01 = 0.f, a10 = 0.f, a11 = 0.f;
        float a20 = 0.f, a21 = 0.f, a30 = 0.f, a31 = 0.f;
        const float* x0 = xb + (size_t)c * HW;
        const float* x1 = x0 + HW;
        #pragma unroll
        for (int k = 0; k < 25; ++k) {
            float v0 = x0[off[k]];
            float v1 = x1[off[k]];
            a00 = fmaf(wt_[k],      v0, a00);  a01 = fmaf(wt_[k],      v1, a01);
            a10 = fmaf(wt_[25 + k], v0, a10);  a11 = fmaf(wt_[25 + k], v1, a11);
            a20 = fmaf(wt_[50 + k], v0, a20);  a21 = fmaf(wt_[50 + k], v1, a21);
            a30 = fmaf(wt_[75 + k], v0, a30);  a31 = fmaf(wt_[75 + k], v1, a31);
        }
        const int r1 = (c >> 1) & 1;
        const int oh = 2 * h + r1;
        const int ow = 2 * w;
        const int cq = c >> 2;
        *(float2*)(ob + (((size_t)(0 * 16 + cq) * 256 + oh) * 256 + ow)) = make_float2(a00, a01);
        *(float2*)(ob + (((size_t)(1 * 16 + cq) * 256 + oh) * 256 + ow)) = make_float2(a10, a11);
        *(float2*)(ob + (((size_t)(2 * 16 + cq) * 256 + oh) * 256 + ow)) = make_float2(a20, a21);
        *(float2*)(ob + (((size_t)(3 * 16 + cq) * 256 + oh) * 256 + ow)) = make_float2(a30, a31);
    }
}

extern "C" void kernel_launch(void* const* d_in, const int* in_sizes, int n_in,
                              void* d_out, int out_size, void* d_ws, size_t ws_size,
                              hipStream_t stream) {
    const float* x  = (const float*)d_in[0];   // [8][64][128][128]
    const float* wc = (const float*)d_in[1];   // [48][64]
    const float* bc = (const float*)d_in[2];   // [48]
    const float* we = (const float*)d_in[3];   // [100][48][3][3]
    const float* be = (const float*)d_in[4];   // [100]
    float* out = (float*)d_out;                // [8][64][256][256]

    // ws: x_t 16,777,216 B | w_t 100,352 B | wc_bf 6,144 B
    __bf16* xt  = (__bf16*)d_ws;
    __bf16* wt  = (__bf16*)((char*)d_ws + 16777216);
    __bf16* wcb = (__bf16*)((char*)d_ws + 16777216 + 100352);

    prep_xt<<<512, 256, 0, stream>>>(x, xt);
    prep_w<<<208, 256, 0, stream>>>(we, wc, wt, wcb);
    carafe_fused<<<512, 256, 0, stream>>>(x, xt, wcb, bc, wt, be, out);
}

// Round 7
// 95.388 us; speedup vs baseline: 11.4238x; 4.3528x over previous
//
#include <hip/hip_runtime.h>

#define HW 16384   // 128*128

typedef __bf16 bf16x8 __attribute__((ext_vector_type(8)));
typedef __bf16 bf16x4 __attribute__((ext_vector_type(4)));
typedef float  f32x4  __attribute__((ext_vector_type(4)));
typedef float  f32x2  __attribute__((ext_vector_type(2)));

// ---------- prep 1: x [b][64][128][128] f32 -> x_t [b][pos][64] bf16 ----------
__global__ __launch_bounds__(256)
void prep_xt(const float* __restrict__ x, __bf16* __restrict__ xt) {
    __shared__ float lds[256 * 65];
    const int b = blockIdx.x & 7, chunk = blockIdx.x >> 3;   // XCD-pin batch
    const int t = threadIdx.x;
    const int pos0 = chunk * 256;
    const float* xb = x + (size_t)b * 64 * HW + pos0;
    for (int c = 0; c < 64; ++c)
        lds[t * 65 + c] = xb[(size_t)c * HW + t];      // coalesced over t
    __syncthreads();
    __bf16* o = xt + ((size_t)b * HW + pos0 + t) * 64;
    #pragma unroll
    for (int j = 0; j < 8; ++j) {
        bf16x8 v;
        #pragma unroll
        for (int e = 0; e < 8; ++e) v[e] = (__bf16)lds[t * 65 + j * 8 + e];
        *(bf16x8*)(o + j * 8) = v;
    }
}

// ---------- prep 2: w_t[112][448] bf16 (k = t*48+m), wc_bf[48][64] bf16 ----------
__global__ __launch_bounds__(256)
void prep_w(const float* __restrict__ we, const float* __restrict__ wc,
            __bf16* __restrict__ wt, __bf16* __restrict__ wcb) {
    int idx = blockIdx.x * 256 + threadIdx.x;
    if (idx < 112 * 448) {
        int e = idx / 448, k = idx % 448;
        float v = 0.f;
        if (e < 100 && k < 432) {
            int t = k / 48, m = k % 48;
            v = we[(e * 48 + m) * 9 + t];
        }
        wt[idx] = (__bf16)v;
    } else {
        idx -= 112 * 448;
        if (idx < 48 * 64) wcb[idx] = (__bf16)wc[idx];
    }
}

// ---------- kernel W: conv1x1(MFMA) -> conv3x3(MFMA) -> softmax -> wnorm fp16 ----------
__global__ __launch_bounds__(256, 2)
void carafe_weights(const __bf16* __restrict__ xt,
                    const __bf16* __restrict__ wcb, const float* __restrict__ bc,
                    const __bf16* __restrict__ wt, const float* __restrict__ be,
                    _Float16* __restrict__ wn) {
    __shared__ __align__(16) char smem[59392];
    __bf16*    y1  = (__bf16*)smem;    // [344][56] (rows=halo pos 18x18 pad + K-pad rows)
    _Float16*  lgt = (_Float16*)smem;  // [256][116] logits (union, after barrier)

    const int tid = threadIdx.x;
    const int lane = tid & 63, wv = tid >> 6;
    const int lgp = lane >> 4, lr = lane & 15;
    const int b = blockIdx.x & 7, tile = blockIdx.x >> 3;    // XCD-pin batch
    const int h0 = (tile >> 3) << 4, w0 = (tile & 7) << 4;

    // ===== P1: y1[pos][m] = relu(conv1x1)  via MFMA, M=336 pos, N=48, K=64
    bf16x8 bw[3][2];
    float bias1[3];
    #pragma unroll
    for (int nt = 0; nt < 3; ++nt) {
        bias1[nt] = bc[nt * 16 + lr];
        #pragma unroll
        for (int kc = 0; kc < 2; ++kc)
            bw[nt][kc] = *(const bf16x8*)(wcb + (nt * 16 + lr) * 64 + kc * 32 + lgp * 8);
    }
    for (int pt = wv; pt < 21; pt += 4) {
        int pos = pt * 16 + lr;
        int pr = (pos * 1821) >> 15;  int pc = pos - pr * 18;   // pos/18, pos%18
        int hy = h0 - 1 + pr, wx = w0 - 1 + pc;
        bool ok = (hy >= 0) & (hy < 128) & (wx >= 0) & (wx < 128);
        const __bf16* ap = xt + ((size_t)b * HW + (ok ? (hy * 128 + wx) : 0)) * 64 + lgp * 8;
        bf16x8 a0 = *(const bf16x8*)ap;
        bf16x8 a1 = *(const bf16x8*)(ap + 32);
        if (!ok) {
            #pragma unroll
            for (int e = 0; e < 8; ++e) { a0[e] = (__bf16)0.f; a1[e] = (__bf16)0.f; }
        }
        #pragma unroll
        for (int nt = 0; nt < 3; ++nt) {
            f32x4 cc = {bias1[nt], bias1[nt], bias1[nt], bias1[nt]};
            cc = __builtin_amdgcn_mfma_f32_16x16x32_bf16(a0, bw[nt][0], cc, 0, 0, 0);
            cc = __builtin_amdgcn_mfma_f32_16x16x32_bf16(a1, bw[nt][1], cc, 0, 0, 0);
            #pragma unroll
            for (int r = 0; r < 4; ++r) {
                int posw = pt * 16 + lgp * 4 + r;
                int pr2 = (posw * 1821) >> 15;  int pc2 = posw - pr2 * 18;
                int hy2 = h0 - 1 + pr2, wx2 = w0 - 1 + pc2;
                bool ok2 = (hy2 >= 0) & (hy2 < 128) & (wx2 >= 0) & (wx2 < 128);
                float v = ok2 ? fmaxf(cc[r], 0.f) : 0.f;   // zero padding for conv3x3
                y1[posw * 56 + nt * 16 + lr] = (__bf16)v;
            }
        }
    }
    // K-padding (t=9) in P2 reads y1 rows 336..339; zero them (NaN*0 = NaN guard)
    for (int i = tid; i < 448; i += 256)
        y1[336 * 56 + i] = (__bf16)0.f;
    __syncthreads();

    // ===== P2: logits[256px][112out] = Ycol[px][432] * W[432][112], K=14x32
    f32x4 acc[4][7];
    #pragma unroll
    for (int ot = 0; ot < 7; ++ot) {
        int o_ = ot * 16 + lr;
        float bz = (o_ < 100) ? be[o_] : 0.f;
        #pragma unroll
        for (int i = 0; i < 4; ++i) acc[i][ot] = {bz, bz, bz, bz};
    }
    const int ptg0 = wv * 4;

    auto ldA = [&](bf16x8 A[4], int kc) {
        int Kb = kc * 32 + lgp * 8;
        int t  = (Kb * 683) >> 15;  int m0 = Kb - t * 48;   // k = t*48+m
        int ty = (t * 11) >> 5;     int tx = t - ty * 3;
        int base = ty * 18 + lr + tx;
        #pragma unroll
        for (int i = 0; i < 4; ++i)
            A[i] = *(const bf16x8*)(y1 + ((ptg0 + i) * 18 + base) * 56 + m0);
    };
    auto ldB = [&](bf16x8 B[7], int kc) {
        #pragma unroll
        for (int j = 0; j < 7; ++j)
            B[j] = *(const bf16x8*)(wt + (j * 16 + lr) * 448 + kc * 32 + lgp * 8);
    };
    auto mm = [&](bf16x8 A[4], bf16x8 B[7]) {
        #pragma unroll
        for (int i = 0; i < 4; ++i)
            #pragma unroll
            for (int j = 0; j < 7; ++j)
                acc[i][j] = __builtin_amdgcn_mfma_f32_16x16x32_bf16(A[i], B[j], acc[i][j], 0, 0, 0);
    };

    bf16x8 A0[4], B0[7], A1[4], B1[7];
    ldA(A0, 0); ldB(B0, 0);
    #pragma unroll
    for (int kc = 0; kc < 14; kc += 2) {
        if (kc + 1 < 14) { ldA(A1, kc + 1); ldB(B1, kc + 1); }
        mm(A0, B0);
        if (kc + 2 < 14) { ldA(A0, kc + 2); ldB(B0, kc + 2); }
        if (kc + 1 < 14) mm(A1, B1);
    }
    __syncthreads();

    // ===== P3: spill logits to LDS [256][116] fp16
    #pragma unroll
    for (int i = 0; i < 4; ++i)
        #pragma unroll
        for (int j = 0; j < 7; ++j) {
            int o_ = j * 16 + lr;
            #pragma unroll
            for (int r = 0; r < 4; ++r) {
                int p = (ptg0 + i) * 16 + lgp * 4 + r;
                lgt[p * 116 + o_] = (_Float16)acc[i][j][r];
            }
        }
    __syncthreads();

    // ===== P4: per-pixel softmax(25) x4 groups -> store fp16 planes (tile-local)
    const int p = tid;
    float wt_[100];
    const _Float16* lrow = lgt + p * 116;
    #pragma unroll
    for (int g = 0; g < 4; ++g) {
        float v[25];
        #pragma unroll
        for (int k = 0; k < 25; ++k) v[k] = (float)lrow[g * 25 + k];
        float mx = v[0];
        #pragma unroll
        for (int k = 1; k < 25; ++k) mx = fmaxf(mx, v[k]);
        float s = 0.f;
        #pragma unroll
        for (int k = 0; k < 25; ++k) { v[k] = __expf(v[k] - mx); s += v[k]; }
        float inv = 1.f / s;
        #pragma unroll
        for (int k = 0; k < 25; ++k) wt_[g * 25 + k] = v[k] * inv;
    }
    _Float16* wp = wn + (size_t)b * 100 * HW + tile * 256 + p;
    #pragma unroll
    for (int j = 0; j < 100; ++j) wp[(size_t)j * HW] = (_Float16)wt_[j];
}

// ---------- kernel A: LDS-staged 5x5 weighted gather + pixel shuffle ----------
// 512 threads: 256 pixels x 2 s-groups. x halo (20x20x64) bf16 in LDS, stride 68.
__global__ __launch_bounds__(512, 4)
void carafe_apply(const __bf16* __restrict__ xt, const _Float16* __restrict__ wn,
                  float* __restrict__ out) {
    __shared__ __bf16 lx[400 * 68];   // 54,400 B; row=halo pos (20x20), col=ch (64, pad 68)

    const int tid = threadIdx.x;
    const int b = blockIdx.x & 7, tile = blockIdx.x >> 3;    // XCD-pin batch
    const int h0 = (tile >> 3) << 4, w0 = (tile & 7) << 4;

    // stage halo from xt (zero-pad outside image)
    const int l8 = tid & 7, pg = tid >> 3;   // 8 lanes x 64 pos-groups
    for (int it = 0; it < 7; ++it) {
        int pos = it * 64 + pg;
        if (pos < 400) {
            int r = pos / 20, q = pos % 20;
            int hy = h0 - 2 + r, wx = w0 - 2 + q;
            bf16x8 v = {};
            if (hy >= 0 && hy < 128 && wx >= 0 && wx < 128)
                v = *(const bf16x8*)(xt + ((size_t)b * HW + hy * 128 + wx) * 64 + l8 * 8);
            bf16x4 vlo = {v[0], v[1], v[2], v[3]};
            bf16x4 vhi = {v[4], v[5], v[6], v[7]};
            *(bf16x4*)(lx + pos * 68 + l8 * 8)     = vlo;   // byte 136*pos+16*l8: 8B-aligned
            *(bf16x4*)(lx + pos * 68 + l8 * 8 + 4) = vhi;
        }
    }

    // 50 normalized weights (2 of 4 s-groups) -> registers
    const int pix = tid & 255, sgrp = tid >> 8;
    const int py = pix >> 4, px = pix & 15;
    const int h = h0 + py, w = w0 + px;
    float wt_[50];
    const _Float16* wp = wn + ((size_t)b * 100 + sgrp * 50) * HW + tile * 256 + pix;
    #pragma unroll
    for (int j = 0; j < 50; ++j) wt_[j] = (float)wp[(size_t)j * HW];

    __syncthreads();

    float* ob = out + (size_t)b * 256 * HW;
    #pragma unroll 1
    for (int cq = 0; cq < 16; ++cq) {          // channels c = 4*cq .. 4*cq+3
        f32x2 a0 = {0.f, 0.f}, a1 = {0.f, 0.f}, a2 = {0.f, 0.f}, a3 = {0.f, 0.f};
        #pragma unroll
        for (int ki = 0; ki < 5; ++ki) {
            const int rowbase = (py + ki) * 20 + px;
            #pragma unroll
            for (int kj = 0; kj < 5; ++kj) {
                uint2 u = *(const uint2*)(lx + (rowbase + kj) * 68 + cq * 4);
                f32x2 xlo = { __uint_as_float(u.x << 16), __uint_as_float(u.x & 0xffff0000u) };
                f32x2 xhi = { __uint_as_float(u.y << 16), __uint_as_float(u.y & 0xffff0000u) };
                float wA = wt_[ki * 5 + kj];
                float wB = wt_[25 + ki * 5 + kj];
                a0 += xlo * wA;   // v_pk_fma_f32 hoped
                a1 += xhi * wA;
                a2 += xlo * wB;
                a3 += xhi * wB;
            }
        }
        // ch C = s*64 + 4cq + d -> plane q = s*16+cq, (r1,r2) = (d>>1, d&1)
        size_t base0 = ((size_t)(sgrp * 32 + cq) * 256 + 2 * h) * 256 + 2 * w;
        *(f32x2*)(ob + base0)       = a0;            // d=0,1 -> row 2h,   cols 2w,2w+1
        *(f32x2*)(ob + base0 + 256) = a1;            // d=2,3 -> row 2h+1
        size_t base1 = base0 + (size_t)16 * 256 * 256;
        *(f32x2*)(ob + base1)       = a2;
        *(f32x2*)(ob + base1 + 256) = a3;
    }
}

extern "C" void kernel_launch(void* const* d_in, const int* in_sizes, int n_in,
                              void* d_out, int out_size, void* d_ws, size_t ws_size,
                              hipStream_t stream) {
    const float* x  = (const float*)d_in[0];   // [8][64][128][128]
    const float* wc = (const float*)d_in[1];   // [48][64]
    const float* bc = (const float*)d_in[2];   // [48]
    const float* we = (const float*)d_in[3];   // [100][48][3][3]
    const float* be = (const float*)d_in[4];   // [100]
    float* out = (float*)d_out;                // [8][64][256][256]

    // ws: xt 16,777,216 | w_t 100,352 | wc_bf 6,144 | wnorm fp16 26,214,400  (~43.1 MB)
    __bf16*   xt  = (__bf16*)d_ws;
    __bf16*   wte = (__bf16*)((char*)d_ws + 16777216);
    __bf16*   wcb = (__bf16*)((char*)d_ws + 16777216 + 100352);
    _Float16* wn  = (_Float16*)((char*)d_ws + 16883712);

    prep_xt<<<512, 256, 0, stream>>>(x, xt);
    prep_w<<<208, 256, 0, stream>>>(we, wc, wte, wcb);
    carafe_weights<<<512, 256, 0, stream>>>(xt, wcb, bc, wte, be, wn);
    carafe_apply<<<512, 512, 0, stream>>>(xt, wn, out);
}